// Round 4
// baseline (308.986 us; speedup 1.0000x reference)
//
#include <hip/hip_runtime.h>
#include <math.h>

#define B_   64
#define L_   500
#define F_   256
#define H_   4
#define DK   64

typedef unsigned short u16;
typedef unsigned int   u32;
typedef __attribute__((ext_vector_type(8))) short short8;
typedef __attribute__((ext_vector_type(4))) float f32x4;

static __device__ __forceinline__ u16 f2bf(float f) {
    u32 u = __float_as_uint(f);
    u32 r = (u + 0x7FFFu + ((u >> 16) & 1u)) >> 16;
    return (u16)r;
}

// ---------------------------------------------------------------------------
// Prep: bf16 transposed weights.
//  wqT/wvT/fcwT [256][256] ([n][k]); w1T[64][64]; w2T[512][64] (n>=500 -> 0)
//  Also zero-fills vhT cols 500..511 (attn chunk-3 frags read them).
//  Grid-stride loops -> launched with 256 blocks (was 64: gather-latency
//  bound on 25% of CUs).
// ---------------------------------------------------------------------------
__global__ __launch_bounds__(256) void prep_kernel(
    const float* __restrict__ wq, const float* __restrict__ wv,
    const float* __restrict__ fcw, const float* __restrict__ w1,
    const float* __restrict__ w2,
    u16* __restrict__ wqT, u16* __restrict__ wvT, u16* __restrict__ fcwT,
    u16* __restrict__ w1T, u16* __restrict__ w2T, u16* __restrict__ vhT)
{
    int t = blockIdx.x * 256 + threadIdx.x;
    int stride = gridDim.x * 256;
    for (int i = t; i < 256 * 256; i += stride) {
        int n = i >> 8, k = i & 255;
        wqT[i]  = f2bf(wq[k * 256 + n]);
        wvT[i]  = f2bf(wv[k * 256 + n]);
        fcwT[i] = f2bf(fcw[k * 256 + n]);
    }
    for (int i = t; i < 64 * 64; i += stride) {
        int n = i >> 6, k = i & 63;
        w1T[i] = f2bf(w1[k * 64 + n]);
    }
    for (int i = t; i < 512 * 64; i += stride) {
        int n = i >> 6, k = i & 63;
        w2T[i] = f2bf(n < 500 ? w2[k * 500 + n] : 0.f);
    }
    // zero vhT padding cols l in [500,512) for every (bh, d)
    for (int i = t; i < 256 * 64 * 12; i += stride) {
        int l  = 500 + (i % 12);
        int d  = (i / 12) & 63;
        int bh = i / (12 * 64);
        vhT[(size_t)(bh * 64 + d) * 512 + l] = 0;
    }
}

// ---------------------------------------------------------------------------
// Kernel 1: head projections, bf16 MFMA.
// grid (500, 2), block 512 = 8 waves in 2x4; block tile 64 rows x 256 cols.
// wave tile 32 x 64.  which=0: qh_bf [bh][500][64]; which=1: vhT [bh][64][512]
// ---------------------------------------------------------------------------
__global__ __launch_bounds__(512) void proj_kernel(
    const float* __restrict__ q, const float* __restrict__ v,
    const u16* __restrict__ wqT, const u16* __restrict__ wvT,
    u16* __restrict__ qh_bf, u16* __restrict__ vhT)
{
    const int which = blockIdx.y;
    const float* __restrict__ x = which ? v : q;
    const u16*   __restrict__ wT = which ? wvT : wqT;

    __shared__ u16 Xs[64][72];    // [m][k], pad 144 B
    __shared__ u16 Ws[256][72];   // [n][k], pad 144 B

    const int tid  = threadIdx.x;
    const int wvid = tid >> 6, ln = tid & 63;
    const int n16  = ln & 15, quad = ln >> 4;
    const int wr   = wvid >> 2, wc = wvid & 3;   // 2 x 4
    const int row0 = blockIdx.x * 64;

    f32x4 acc[2][4];
    #pragma unroll
    for (int mt = 0; mt < 2; mt++)
        #pragma unroll
        for (int nt = 0; nt < 4; nt++) acc[mt][nt] = (f32x4){0.f, 0.f, 0.f, 0.f};

    for (int kc = 0; kc < 256; kc += 64) {
        // stage X (fp32 -> bf16): 64 x 64
        #pragma unroll
        for (int j = 0; j < 2; j++) {
            int idx = tid + 512 * j;
            int m = idx >> 4, k4 = idx & 15;
            float4 a = *(const float4*)&x[(size_t)(row0 + m) * 256 + kc + k4 * 4];
            __align__(8) u16 t4[4] = {f2bf(a.x), f2bf(a.y), f2bf(a.z), f2bf(a.w)};
            *(uint2*)&Xs[m][k4 * 4] = *(const uint2*)t4;
        }
        // stage W^T: 256 x 64 bf16
        #pragma unroll
        for (int j = 0; j < 4; j++) {
            int idx = tid + 512 * j;
            int n = idx >> 3, k8 = idx & 7;
            *(uint4*)&Ws[n][k8 * 8] = *(const uint4*)&wT[n * 256 + kc + k8 * 8];
        }
        __syncthreads();
        #pragma unroll
        for (int ks = 0; ks < 2; ks++) {
            short8 af[2], bfr[4];
            #pragma unroll
            for (int mt = 0; mt < 2; mt++)
                af[mt] = *(const short8*)&Xs[wr * 32 + mt * 16 + n16][ks * 32 + quad * 8];
            #pragma unroll
            for (int nt = 0; nt < 4; nt++)
                bfr[nt] = *(const short8*)&Ws[wc * 64 + nt * 16 + n16][ks * 32 + quad * 8];
            #pragma unroll
            for (int mt = 0; mt < 2; mt++)
                #pragma unroll
                for (int nt = 0; nt < 4; nt++)
                    acc[mt][nt] = __builtin_amdgcn_mfma_f32_16x16x32_bf16(
                        af[mt], bfr[nt], acc[mt][nt], 0, 0, 0);
        }
        __syncthreads();
    }

    // h = wc (64-col groups), d = nt*16 + n16
    if (which == 0) {
        #pragma unroll
        for (int mt = 0; mt < 2; mt++) {
            int m0 = row0 + wr * 32 + mt * 16 + quad * 4;   // mult of 4
            int b  = m0 / 500;
            int l0 = m0 - 500 * b;                           // group never straddles b
            #pragma unroll
            for (int nt = 0; nt < 4; nt++) {
                int d = nt * 16 + n16;
                u16* dst = qh_bf + ((size_t)((b * 4 + wc) * 500 + l0)) * 64 + d;
                #pragma unroll
                for (int i = 0; i < 4; i++)
                    dst[(size_t)i * 64] = f2bf(acc[mt][nt][i]);
            }
        }
    } else {
        #pragma unroll
        for (int mt = 0; mt < 2; mt++) {
            int m0 = row0 + wr * 32 + mt * 16 + quad * 4;
            int b  = m0 / 500;
            int l0 = m0 - 500 * b;
            #pragma unroll
            for (int nt = 0; nt < 4; nt++) {
                int d = nt * 16 + n16;
                __align__(8) u16 t4[4];
                #pragma unroll
                for (int i = 0; i < 4; i++) t4[i] = f2bf(acc[mt][nt][i]);
                *(uint2*)&vhT[((size_t)((b * 4 + wc) * 64 + d)) * 512 + l0] =
                    *(const uint2*)t4;
            }
        }
    }
}

// ---------------------------------------------------------------------------
// Kernel 2: dense-synthesizer attention, flash-style online softmax,
// ZERO barriers. grid (256 bh, 8 row-chunks), block 256 (4 waves x 16 rows).
// w2 (64 KB) and V (64 KB/bh) are L2-resident (all 8 row-chunk blocks of a
// bh land on one XCD: id = x+256y, 256 % 8 == 0) -> both consumed as
// register B-frags loaded STRAIGHT from global; the per-lane addresses are
// the composition of round-0's staging-write + LDS-read mappings (proven).
// Only LDS: the per-wave-private P tile -> no inter-wave dependency at all;
// waves run free, loads hoist across former barrier points.
// LDS = 17 KB. W-frags for chunk cc+1 prefetched during softmax/PV of cc.
// ---------------------------------------------------------------------------
__global__ __launch_bounds__(256) void attn_kernel(
    const u16* __restrict__ qh, const u16* __restrict__ vhT,
    const u16* __restrict__ w1T, const float* __restrict__ b1,
    const u16* __restrict__ w2T, const float* __restrict__ b2,
    u16* __restrict__ ctx)
{
    __shared__ __align__(16) u16 pls[4][16][136];   // per-wave P / s tile

    const int tid  = threadIdx.x;
    const int wv   = tid >> 6;
    const int ln   = tid & 63;
    const int n16  = ln & 15;
    const int quad = ln >> 4;
    const int bh   = blockIdx.x;
    const int r0   = blockIdx.y * 64 + wv * 16;

    const u16* __restrict__ vgbase = vhT + (size_t)bh * 64 * 512;
    u16 (*pw)[136] = pls[wv];

    // ---- W chunk-0 frags (issued first; land under Phase A) ----
    short8 rW0[8], rW1[8];
    #pragma unroll
    for (int t = 0; t < 8; t++) {
        const u16* p = &w2T[(size_t)(t * 16 + n16) * 64 + quad * 8];
        rW0[t] = *(const short8*)p;
        rW1[t] = *(const short8*)(p + 32);
    }

    // ---- Phase A: s = relu(qh @ w1 + b1) -> per-wave LDS -> A-frags ----
    // (in-wave DS write->read, no barrier: r3-proven)
    short8 sa0, sa1;
    {
        const u16* qbase = qh + ((size_t)(bh * 500 + r0 + n16)) * 64;
        short8 a0 = *(const short8*)(qbase + quad * 8);
        short8 a1 = *(const short8*)(qbase + 32 + quad * 8);
        #pragma unroll
        for (int nt = 0; nt < 4; nt++) {
            const u16* wb = w1T + (nt * 16 + n16) * 64;
            short8 bb0 = *(const short8*)(wb + quad * 8);
            short8 bb1 = *(const short8*)(wb + 32 + quad * 8);
            f32x4 c4 = {0.f, 0.f, 0.f, 0.f};
            c4 = __builtin_amdgcn_mfma_f32_16x16x32_bf16(a0, bb0, c4, 0, 0, 0);
            c4 = __builtin_amdgcn_mfma_f32_16x16x32_bf16(a1, bb1, c4, 0, 0, 0);
            float bias = b1[nt * 16 + n16];
            #pragma unroll
            for (int i = 0; i < 4; i++)
                pw[quad * 4 + i][nt * 16 + n16] = f2bf(fmaxf(c4[i] + bias, 0.f));
        }
        sa0 = *(const short8*)&pw[n16][quad * 8];
        sa1 = *(const short8*)&pw[n16][32 + quad * 8];
    }

    f32x4 oacc[4];
    #pragma unroll
    for (int nt = 0; nt < 4; nt++) oacc[nt] = (f32x4){0.f, 0.f, 0.f, 0.f};
    float m_[4], l_[4];
    #pragma unroll
    for (int i = 0; i < 4; i++) { m_[i] = -INFINITY; l_[i] = 0.f; }

    #pragma unroll
    for (int cc = 0; cc < 4; cc++) {
        // ---- logits from register W-frags ----
        f32x4 c[8];
        #pragma unroll
        for (int t = 0; t < 8; t++) {
            f32x4 a = {0.f, 0.f, 0.f, 0.f};
            a = __builtin_amdgcn_mfma_f32_16x16x32_bf16(sa0, rW0[t], a, 0, 0, 0);
            a = __builtin_amdgcn_mfma_f32_16x16x32_bf16(sa1, rW1[t], a, 0, 0, 0);
            int col = cc * 128 + t * 16 + n16;
            float bias = (col < 500) ? b2[col] : -INFINITY;
            #pragma unroll
            for (int i = 0; i < 4; i++) c[t][i] = a[i] + bias;
        }
        // prefetch W-frags for chunk cc+1 (rW dead; lands under softmax/PV)
        if (cc < 3) {
            #pragma unroll
            for (int t = 0; t < 8; t++) {
                const u16* p = &w2T[(size_t)((cc + 1) * 128 + t * 16 + n16) * 64 + quad * 8];
                rW0[t] = *(const short8*)p;
                rW1[t] = *(const short8*)(p + 32);
            }
        }

        // ---- online softmax update ----
        {
            float cm[4];
            #pragma unroll
            for (int i = 0; i < 4; i++) cm[i] = c[0][i];
            #pragma unroll
            for (int t = 1; t < 8; t++)
                #pragma unroll
                for (int i = 0; i < 4; i++) cm[i] = fmaxf(cm[i], c[t][i]);
            #pragma unroll
            for (int off = 1; off < 16; off <<= 1)
                #pragma unroll
                for (int i = 0; i < 4; i++) cm[i] = fmaxf(cm[i], __shfl_xor(cm[i], off));
            #pragma unroll
            for (int i = 0; i < 4; i++) {
                float Mn = fmaxf(m_[i], cm[i]);
                float sc = __expf(m_[i] - Mn);    // cc==0: exp(-inf)=0
                m_[i] = Mn;
                l_[i] *= sc;
                #pragma unroll
                for (int nt = 0; nt < 4; nt++) oacc[nt][i] *= sc;
            }
        }

        // ---- exp -> bf16 P into per-wave LDS; row-sum partials ----
        #pragma unroll
        for (int t = 0; t < 8; t++) {
            int colb = t * 16 + n16;
            #pragma unroll
            for (int i = 0; i < 4; i++) {
                float e = __expf(c[t][i] - m_[i]);
                l_[i] += e;
                pw[quad * 4 + i][colb] = f2bf(e);
            }
        }

        // ---- PV: V B-frags straight from global (L2-resident) ----
        #pragma unroll
        for (int ks = 0; ks < 4; ks++) {
            short8 pa = *(const short8*)&pw[n16][ks * 32 + quad * 8];
            #pragma unroll
            for (int nt = 0; nt < 4; nt++) {
                short8 vv = *(const short8*)&vgbase[
                    (size_t)(nt * 16 + n16) * 512 + cc * 128 + ks * 32 + quad * 8];
                oacc[nt] = __builtin_amdgcn_mfma_f32_16x16x32_bf16(pa, vv, oacc[nt], 0, 0, 0);
            }
        }
    }

    // ---- epilogue: reduce l, scale, write ctx bf16 ----
    {
        #pragma unroll
        for (int off = 1; off < 16; off <<= 1)
            #pragma unroll
            for (int i = 0; i < 4; i++) l_[i] += __shfl_xor(l_[i], off);
        const int b = bh >> 2, h = bh & 3;
        #pragma unroll
        for (int i = 0; i < 4; i++) {
            int lrow = r0 + quad * 4 + i;
            if (lrow < 500) {
                float s = 1.f / l_[i];
                u16* dst = &ctx[((size_t)(b * 500 + lrow)) * 256 + h * 64];
                #pragma unroll
                for (int nt = 0; nt < 4; nt++)
                    dst[nt * 16 + n16] = f2bf(oacc[nt][i] * s);
            }
        }
    }
}

// ---------------------------------------------------------------------------
// Kernel 3: out = LayerNorm(ctx @ fc_w + q), bf16 MFMA + fused LN epilogue.
// grid (500), block 512 = 8 waves in 2x4; block tile 64 rows x 256 cols.
// ---------------------------------------------------------------------------
__global__ __launch_bounds__(512) void final_kernel(
    const u16* __restrict__ ctx, const u16* __restrict__ fcwT,
    const float* __restrict__ qres, const float* __restrict__ g,
    const float* __restrict__ bta, float* __restrict__ out)
{
    __shared__ u16 Xs[64][72];
    __shared__ u16 Ws[256][72];
    __shared__ float red[4][2][64];   // [wc][s1|s2][row]
    __shared__ float murs[2][64];     // [mu|rs][row]

    const int tid  = threadIdx.x;
    const int wvid = tid >> 6, ln = tid & 63;
    const int n16  = ln & 15, quad = ln >> 4;
    const int wr   = wvid >> 2, wc = wvid & 3;   // 2 x 4
    const int row0 = blockIdx.x * 64;

    f32x4 acc[2][4];
    #pragma unroll
    for (int mt = 0; mt < 2; mt++)
        #pragma unroll
        for (int nt = 0; nt < 4; nt++) acc[mt][nt] = (f32x4){0.f, 0.f, 0.f, 0.f};

    for (int kc = 0; kc < 256; kc += 64) {
        // stage X: 64 x 64 bf16
        {
            int idx = tid;
            int m = idx >> 3, k8 = idx & 7;
            *(uint4*)&Xs[m][k8 * 8] =
                *(const uint4*)&ctx[(size_t)(row0 + m) * 256 + kc + k8 * 8];
        }
        // stage W^T: 256 x 64 bf16
        #pragma unroll
        for (int j = 0; j < 4; j++) {
            int idx = tid + 512 * j;
            int n = idx >> 3, k8 = idx & 7;
            *(uint4*)&Ws[n][k8 * 8] = *(const uint4*)&fcwT[n * 256 + kc + k8 * 8];
        }
        __syncthreads();
        #pragma unroll
        for (int ks = 0; ks < 2; ks++) {
            short8 af[2], bfr[4];
            #pragma unroll
            for (int mt = 0; mt < 2; mt++)
                af[mt] = *(const short8*)&Xs[wr * 32 + mt * 16 + n16][ks * 32 + quad * 8];
            #pragma unroll
            for (int nt = 0; nt < 4; nt++)
                bfr[nt] = *(const short8*)&Ws[wc * 64 + nt * 16 + n16][ks * 32 + quad * 8];
            #pragma unroll
            for (int mt = 0; mt < 2; mt++)
                #pragma unroll
                for (int nt = 0; nt < 4; nt++)
                    acc[mt][nt] = __builtin_amdgcn_mfma_f32_16x16x32_bf16(
                        af[mt], bfr[nt], acc[mt][nt], 0, 0, 0);
        }
        __syncthreads();
    }

    // residual add
    #pragma unroll
    for (int mt = 0; mt < 2; mt++) {
        int m0 = row0 + wr * 32 + mt * 16 + quad * 4;
        #pragma unroll
        for (int i = 0; i < 4; i++) {
            const float* rp = &qres[(size_t)(m0 + i) * 256 + wc * 64 + n16];
            #pragma unroll
            for (int nt = 0; nt < 4; nt++)
                acc[mt][nt][i] += rp[nt * 16];
        }
    }
    // per-row partial sums -> LDS
    #pragma unroll
    for (int mt = 0; mt < 2; mt++) {
        #pragma unroll
        for (int i = 0; i < 4; i++) {
            float s1 = 0.f, s2 = 0.f;
            #pragma unroll
            for (int nt = 0; nt < 4; nt++) {
                float vv = acc[mt][nt][i];
                s1 += vv; s2 += vv * vv;
            }
            #pragma unroll
            for (int off = 1; off < 16; off <<= 1) {
                s1 += __shfl_xor(s1, off);
                s2 += __shfl_xor(s2, off);
            }
            if (n16 == 0) {
                int r = wr * 32 + mt * 16 + quad * 4 + i;
                red[wc][0][r] = s1;
                red[wc][1][r] = s2;
            }
        }
    }
    __syncthreads();
    if (tid < 64) {
        float S1 = red[0][0][tid] + red[1][0][tid] + red[2][0][tid] + red[3][0][tid];
        float S2 = red[0][1][tid] + red[1][1][tid] + red[2][1][tid] + red[3][1][tid];
        float mu  = S1 * 0.00390625f;
        float var = S2 * 0.00390625f - mu * mu;
        murs[0][tid] = mu;
        murs[1][tid] = rsqrtf(var + 1e-6f);
    }
    __syncthreads();

    float gv[4], bv[4];
    #pragma unroll
    for (int nt = 0; nt < 4; nt++) {
        int col = wc * 64 + nt * 16 + n16;
        gv[nt] = g[col];
        bv[nt] = bta[col];
    }
    #pragma unroll
    for (int mt = 0; mt < 2; mt++) {
        int rb = wr * 32 + mt * 16 + quad * 4;
        #pragma unroll
        for (int i = 0; i < 4; i++) {
            float mu = murs[0][rb + i];
            float rs = murs[1][rb + i];
            float* op = &out[(size_t)(row0 + rb + i) * 256 + wc * 64 + n16];
            #pragma unroll
            for (int nt = 0; nt < 4; nt++)
                op[nt * 16] = (acc[mt][nt][i] - mu) * rs * gv[nt] + bv[nt];
        }
    }
}

// ---------------------------------------------------------------------------
extern "C" void kernel_launch(void* const* d_in, const int* in_sizes, int n_in,
                              void* d_out, int out_size, void* d_ws, size_t ws_size,
                              hipStream_t stream)
{
    const float* q   = (const float*)d_in[0];
    const float* v   = (const float*)d_in[2];
    const float* wqs = (const float*)d_in[3];
    const float* wvs = (const float*)d_in[4];
    const float* w1  = (const float*)d_in[5];
    const float* b1  = (const float*)d_in[6];
    const float* w2  = (const float*)d_in[7];
    const float* b2  = (const float*)d_in[8];
    const float* fcw = (const float*)d_in[9];
    const float* lng = (const float*)d_in[10];
    const float* lnb = (const float*)d_in[11];
    float* out = (float*)d_out;

    u16* qh_bf = (u16*)d_ws;            // 8,200,192 (padded: attn reads rows <512)
    u16* vhT   = qh_bf + 8200192;       // 8,388,608  [bh][64][512]
    u16* w1T   = vhT + 8388608;         // 4,096
    u16* w2T   = w1T + 4096;            // 32,768     [512][64]
    u16* wqT   = w2T + 32768;           // 65,536
    u16* wvT   = wqT + 65536;           // 65,536
    u16* fcwT  = wvT + 65536;           // 65,536
    u16* ctx   = fcwT + 65536;          // 8,192,000

    prep_kernel <<<dim3(256),    256, 0, stream>>>(wqs, wvs, fcw, w1, w2,
                                                   wqT, wvT, fcwT, w1T, w2T, vhT);
    proj_kernel <<<dim3(500, 2), 512, 0, stream>>>(q, v, wqT, wvT, qh_bf, vhT);
    attn_kernel <<<dim3(256, 8), 256, 0, stream>>>(qh_bf, vhT, w1T, b1, w2T, b2, ctx);
    final_kernel<<<dim3(500),    512, 0, stream>>>(ctx, fcwT, q, lng, lnb, out);
}

// Round 5
// 238.834 us; speedup vs baseline: 1.2937x; 1.2937x over previous
//
#include <hip/hip_runtime.h>
#include <math.h>

#define B_   64
#define L_   500
#define F_   256
#define H_   4
#define DK   64

typedef unsigned short u16;
typedef unsigned int   u32;
typedef __attribute__((ext_vector_type(8))) short short8;
typedef __attribute__((ext_vector_type(4))) float f32x4;

static __device__ __forceinline__ u16 f2bf(float f) {
    u32 u = __float_as_uint(f);
    u32 r = (u + 0x7FFFu + ((u >> 16) & 1u)) >> 16;
    return (u16)r;
}

// ---------------------------------------------------------------------------
// Prep: bf16 transposed weights.
//  wqT/wvT/fcwT [256][256] ([n][k]); w1T[64][64]; w2T[512][64] (n>=500 -> 0)
//  Also zero-fills vhT cols 500..511 (attn chunk-3 staging reads them).
// ---------------------------------------------------------------------------
__global__ __launch_bounds__(256) void prep_kernel(
    const float* __restrict__ wq, const float* __restrict__ wv,
    const float* __restrict__ fcw, const float* __restrict__ w1,
    const float* __restrict__ w2,
    u16* __restrict__ wqT, u16* __restrict__ wvT, u16* __restrict__ fcwT,
    u16* __restrict__ w1T, u16* __restrict__ w2T, u16* __restrict__ vhT)
{
    int t = blockIdx.x * 256 + threadIdx.x;
    int stride = gridDim.x * 256;
    for (int i = t; i < 256 * 256; i += stride) {
        int n = i >> 8, k = i & 255;
        wqT[i]  = f2bf(wq[k * 256 + n]);
        wvT[i]  = f2bf(wv[k * 256 + n]);
        fcwT[i] = f2bf(fcw[k * 256 + n]);
    }
    for (int i = t; i < 64 * 64; i += stride) {
        int n = i >> 6, k = i & 63;
        w1T[i] = f2bf(w1[k * 64 + n]);
    }
    for (int i = t; i < 512 * 64; i += stride) {
        int n = i >> 6, k = i & 63;
        w2T[i] = f2bf(n < 500 ? w2[k * 500 + n] : 0.f);
    }
    // zero vhT padding cols l in [500,512) for every (bh, d)
    for (int i = t; i < 256 * 64 * 12; i += stride) {
        int l  = 500 + (i % 12);
        int d  = (i / 12) & 63;
        int bh = i / (12 * 64);
        vhT[(size_t)(bh * 64 + d) * 512 + l] = 0;
    }
}

// ---------------------------------------------------------------------------
// Kernel 1: head projections, bf16 MFMA.
// grid (500, 2), block 512 = 8 waves in 2x4; block tile 64 rows x 256 cols.
// wave tile 32 x 64.  which=0: qh_bf [bh][500][64]; which=1: vhT [bh][64][512]
// ---------------------------------------------------------------------------
__global__ __launch_bounds__(512) void proj_kernel(
    const float* __restrict__ q, const float* __restrict__ v,
    const u16* __restrict__ wqT, const u16* __restrict__ wvT,
    u16* __restrict__ qh_bf, u16* __restrict__ vhT)
{
    const int which = blockIdx.y;
    const float* __restrict__ x = which ? v : q;
    const u16*   __restrict__ wT = which ? wvT : wqT;

    __shared__ u16 Xs[64][72];    // [m][k], pad 144 B
    __shared__ u16 Ws[256][72];   // [n][k], pad 144 B

    const int tid  = threadIdx.x;
    const int wvid = tid >> 6, ln = tid & 63;
    const int n16  = ln & 15, quad = ln >> 4;
    const int wr   = wvid >> 2, wc = wvid & 3;   // 2 x 4
    const int row0 = blockIdx.x * 64;

    f32x4 acc[2][4];
    #pragma unroll
    for (int mt = 0; mt < 2; mt++)
        #pragma unroll
        for (int nt = 0; nt < 4; nt++) acc[mt][nt] = (f32x4){0.f, 0.f, 0.f, 0.f};

    for (int kc = 0; kc < 256; kc += 64) {
        // stage X (fp32 -> bf16): 64 x 64
        #pragma unroll
        for (int j = 0; j < 2; j++) {
            int idx = tid + 512 * j;
            int m = idx >> 4, k4 = idx & 15;
            float4 a = *(const float4*)&x[(size_t)(row0 + m) * 256 + kc + k4 * 4];
            __align__(8) u16 t4[4] = {f2bf(a.x), f2bf(a.y), f2bf(a.z), f2bf(a.w)};
            *(uint2*)&Xs[m][k4 * 4] = *(const uint2*)t4;
        }
        // stage W^T: 256 x 64 bf16
        #pragma unroll
        for (int j = 0; j < 4; j++) {
            int idx = tid + 512 * j;
            int n = idx >> 3, k8 = idx & 7;
            *(uint4*)&Ws[n][k8 * 8] = *(const uint4*)&wT[n * 256 + kc + k8 * 8];
        }
        __syncthreads();
        #pragma unroll
        for (int ks = 0; ks < 2; ks++) {
            short8 af[2], bfr[4];
            #pragma unroll
            for (int mt = 0; mt < 2; mt++)
                af[mt] = *(const short8*)&Xs[wr * 32 + mt * 16 + n16][ks * 32 + quad * 8];
            #pragma unroll
            for (int nt = 0; nt < 4; nt++)
                bfr[nt] = *(const short8*)&Ws[wc * 64 + nt * 16 + n16][ks * 32 + quad * 8];
            #pragma unroll
            for (int mt = 0; mt < 2; mt++)
                #pragma unroll
                for (int nt = 0; nt < 4; nt++)
                    acc[mt][nt] = __builtin_amdgcn_mfma_f32_16x16x32_bf16(
                        af[mt], bfr[nt], acc[mt][nt], 0, 0, 0);
        }
        __syncthreads();
    }

    // h = wc (64-col groups), d = nt*16 + n16
    if (which == 0) {
        #pragma unroll
        for (int mt = 0; mt < 2; mt++) {
            int m0 = row0 + wr * 32 + mt * 16 + quad * 4;   // mult of 4
            int b  = m0 / 500;
            int l0 = m0 - 500 * b;                           // group never straddles b
            #pragma unroll
            for (int nt = 0; nt < 4; nt++) {
                int d = nt * 16 + n16;
                u16* dst = qh_bf + ((size_t)((b * 4 + wc) * 500 + l0)) * 64 + d;
                #pragma unroll
                for (int i = 0; i < 4; i++)
                    dst[(size_t)i * 64] = f2bf(acc[mt][nt][i]);
            }
        }
    } else {
        #pragma unroll
        for (int mt = 0; mt < 2; mt++) {
            int m0 = row0 + wr * 32 + mt * 16 + quad * 4;
            int b  = m0 / 500;
            int l0 = m0 - 500 * b;
            #pragma unroll
            for (int nt = 0; nt < 4; nt++) {
                int d = nt * 16 + n16;
                __align__(8) u16 t4[4];
                #pragma unroll
                for (int i = 0; i < 4; i++) t4[i] = f2bf(acc[mt][nt][i]);
                *(uint2*)&vhT[((size_t)((b * 4 + wc) * 64 + d)) * 512 + l0] =
                    *(const uint2*)t4;
            }
        }
    }
}

// ---------------------------------------------------------------------------
// Kernel 2: dense-synthesizer attention (r0 structure, stalls removed).
// grid (256 bh, 8 row-chunks), block 256 (4 waves x 16 rows).
// - Phase A barrier-free in per-wave-private P region (r3/r4-proven).
// - Phase B: w2 LDS double-buffer (r0), but T14 write-late: next-chunk
//   loads issue BEFORE the 16 MFMAs, ds_write after -> vmcnt wait covered.
// - Full softmax over acc[32] (r0); V0 global loads issued just before it,
//   so softmax VALU covers their latency.
// - Phase C: V double-buffered; V(cc+1) loads issued between P-write and
//   PV (PV covers L2 latency), ds_write after PV, one sync per chunk.
// - V buffers alias the dead w2 LDS region (union). LDS = 54,272 B.
// Barriers: 9 (r0: 12), none with uncovered staging latency behind it.
// ---------------------------------------------------------------------------
__global__ __launch_bounds__(256) void attn_kernel(
    const u16* __restrict__ qh, const u16* __restrict__ vhT,
    const u16* __restrict__ w1T, const float* __restrict__ b1,
    const u16* __restrict__ w2T, const float* __restrict__ b2,
    u16* __restrict__ ctx)
{
    __shared__ __align__(16) char lds_raw[36864];   // w2 dbuf | V dbuf (union)
    __shared__ __align__(16) u16 pls[4][16][136];   // per-wave s/P tile
    u16 (*w2s)[128][72] = (u16 (*)[128][72]) lds_raw;           // [2][128][72]
    u16 (*vbufA)[136]   = (u16 (*)[136]) lds_raw;               // [64][136]
    u16 (*vbufB)[136]   = (u16 (*)[136]) (lds_raw + 17408);     // [64][136]

    const int tid  = threadIdx.x;
    const int wv   = tid >> 6;
    const int ln   = tid & 63;
    const int n16  = ln & 15;
    const int quad = ln >> 4;
    const int bh   = blockIdx.x;
    const int r0   = blockIdx.y * 64 + wv * 16;

    const u16* __restrict__ vgbase = vhT + (size_t)bh * 64 * 512;
    u16 (*pw)[136] = pls[wv];

    // ---- issue w2 chunk-0 staging loads (land during Phase A) ----
    uint4 rw[4];
    #pragma unroll
    for (int j = 0; j < 4; j++) {
        int idx = tid + 256 * j;
        rw[j] = *(const uint4*)&w2T[idx * 8];
    }

    // ---- Phase A: s = relu(qh @ w1 + b1) -> private LDS -> A-frags ----
    short8 sa0, sa1;
    {
        const u16* qbase = qh + ((size_t)(bh * 500 + r0 + n16)) * 64;
        short8 a0 = *(const short8*)(qbase + quad * 8);
        short8 a1 = *(const short8*)(qbase + 32 + quad * 8);
        #pragma unroll
        for (int nt = 0; nt < 4; nt++) {
            const u16* wb = w1T + (nt * 16 + n16) * 64;
            short8 bb0 = *(const short8*)(wb + quad * 8);
            short8 bb1 = *(const short8*)(wb + 32 + quad * 8);
            f32x4 c4 = {0.f, 0.f, 0.f, 0.f};
            c4 = __builtin_amdgcn_mfma_f32_16x16x32_bf16(a0, bb0, c4, 0, 0, 0);
            c4 = __builtin_amdgcn_mfma_f32_16x16x32_bf16(a1, bb1, c4, 0, 0, 0);
            float bias = b1[nt * 16 + n16];
            #pragma unroll
            for (int i = 0; i < 4; i++)
                pw[quad * 4 + i][nt * 16 + n16] = f2bf(fmaxf(c4[i] + bias, 0.f));
        }
        sa0 = *(const short8*)&pw[n16][quad * 8];
        sa1 = *(const short8*)&pw[n16][32 + quad * 8];
    }

    // ---- write w2 chunk 0, publish ----
    #pragma unroll
    for (int j = 0; j < 4; j++) {
        int idx = tid + 256 * j;
        *(uint4*)&w2s[0][idx >> 3][(idx & 7) * 8] = rw[j];
    }
    __syncthreads();                                     // sync 1

    // ---- Phase B: logits = s @ w2 + b2, w2 double-buffered, write-late ----
    f32x4 acc[32];
    for (int cc = 0; cc < 4; cc++) {
        if (cc < 3) {
            const u16* src = w2T + (cc + 1) * 8192;
            #pragma unroll
            for (int j = 0; j < 4; j++) {
                int idx = tid + 256 * j;
                rw[j] = *(const uint4*)&src[idx * 8];
            }
        }
        u16 (*buf)[72] = w2s[cc & 1];
        #pragma unroll
        for (int t = 0; t < 8; t++) {
            int nt = cc * 8 + t;
            short8 bb0 = *(const short8*)&buf[t * 16 + n16][quad * 8];
            short8 bb1 = *(const short8*)&buf[t * 16 + n16][32 + quad * 8];
            f32x4 c = {0.f, 0.f, 0.f, 0.f};
            c = __builtin_amdgcn_mfma_f32_16x16x32_bf16(sa0, bb0, c, 0, 0, 0);
            c = __builtin_amdgcn_mfma_f32_16x16x32_bf16(sa1, bb1, c, 0, 0, 0);
            int col = cc * 8 * 16 + t * 16 + n16 + cc * 0;   // = cc*128 + t*16 + n16
            col = cc * 128 + t * 16 + n16;
            float bias = (col < 500) ? b2[col] : -INFINITY;
            #pragma unroll
            for (int i = 0; i < 4; i++) c[i] += bias;
            acc[nt] = c;
        }
        if (cc < 3) {
            #pragma unroll
            for (int j = 0; j < 4; j++) {
                int idx = tid + 256 * j;
                *(uint4*)&w2s[(cc + 1) & 1][idx >> 3][(idx & 7) * 8] = rw[j];
            }
        }
        __syncthreads();                                 // sync 2-5
    }

    // ---- issue V chunk-0 loads (softmax covers their latency) ----
    short8 rV[4];
    #pragma unroll
    for (int jj = 0; jj < 4; jj++) {
        int u = tid + 256 * jj, d = u >> 4, kk = (u & 15) * 8;
        rV[jj] = *(const short8*)&vgbase[(size_t)d * 512 + kk];
    }

    // ---- softmax stats (P unnormalized; fold 1/sum into epilogue) ----
    float inv[4];
    {
        float mx[4], sm[4];
        #pragma unroll
        for (int i = 0; i < 4; i++) mx[i] = acc[0][i];
        #pragma unroll
        for (int nt = 1; nt < 32; nt++)
            #pragma unroll
            for (int i = 0; i < 4; i++) mx[i] = fmaxf(mx[i], acc[nt][i]);
        #pragma unroll
        for (int off = 1; off < 16; off <<= 1)
            #pragma unroll
            for (int i = 0; i < 4; i++) mx[i] = fmaxf(mx[i], __shfl_xor(mx[i], off));
        #pragma unroll
        for (int i = 0; i < 4; i++) sm[i] = 0.f;
        #pragma unroll
        for (int nt = 0; nt < 32; nt++)
            #pragma unroll
            for (int i = 0; i < 4; i++) {
                float e = __expf(acc[nt][i] - mx[i]);
                acc[nt][i] = e;
                sm[i] += e;
            }
        #pragma unroll
        for (int off = 1; off < 16; off <<= 1)
            #pragma unroll
            for (int i = 0; i < 4; i++) sm[i] += __shfl_xor(sm[i], off);
        #pragma unroll
        for (int i = 0; i < 4; i++) inv[i] = 1.f / sm[i];
    }

    // ---- write V0 -> bufA, publish ----
    #pragma unroll
    for (int jj = 0; jj < 4; jj++) {
        int u = tid + 256 * jj, d = u >> 4, kk = (u & 15) * 8;
        *(short8*)&vbufA[d][kk] = rV[jj];
    }
    __syncthreads();                                     // sync 6

    // ---- Phase C: out = P @ vh, V double-buffered ----
    f32x4 oacc[4];
    #pragma unroll
    for (int nt = 0; nt < 4; nt++) oacc[nt] = (f32x4){0.f, 0.f, 0.f, 0.f};

    for (int cc = 0; cc < 4; cc++) {
        u16 (*vb)[136] = (cc & 1) ? vbufB : vbufA;
        u16 (*vn)[136] = (cc & 1) ? vbufA : vbufB;

        // P for this chunk (per-wave private, no barrier)
        #pragma unroll
        for (int t = 0; t < 8; t++) {
            int nt = cc * 8 + t;
            int c  = t * 16 + n16;
            #pragma unroll
            for (int i = 0; i < 4; i++)
                pw[quad * 4 + i][c] = f2bf(acc[nt][i]);
        }
        // issue V(cc+1) loads; PV below covers their latency
        if (cc < 3) {
            #pragma unroll
            for (int jj = 0; jj < 4; jj++) {
                int u = tid + 256 * jj, d = u >> 4, kk = (u & 15) * 8;
                rV[jj] = *(const short8*)&vgbase[(size_t)d * 512 + (cc + 1) * 128 + kk];
            }
        }
        // PV MFMAs
        #pragma unroll
        for (int ks = 0; ks < 4; ks++) {
            short8 pa = *(const short8*)&pw[n16][ks * 32 + quad * 8];
            #pragma unroll
            for (int nt = 0; nt < 4; nt++) {
                short8 vvf = *(const short8*)&vb[nt * 16 + n16][ks * 32 + quad * 8];
                oacc[nt] = __builtin_amdgcn_mfma_f32_16x16x32_bf16(pa, vvf, oacc[nt], 0, 0, 0);
            }
        }
        // write-late V(cc+1) into the other buffer (WAR drained by prev sync)
        if (cc < 3) {
            #pragma unroll
            for (int jj = 0; jj < 4; jj++) {
                int u = tid + 256 * jj, d = u >> 4, kk = (u & 15) * 8;
                *(short8*)&vn[d][kk] = rV[jj];
            }
            __syncthreads();                             // sync 7-9
        }
    }

    // ---- epilogue: scale, write ctx bf16 ----
    {
        const int b = bh >> 2, h = bh & 3;
        #pragma unroll
        for (int i = 0; i < 4; i++) {
            int lrow = r0 + quad * 4 + i;
            if (lrow < 500) {
                float s = inv[i];
                u16* dst = &ctx[((size_t)(b * 500 + lrow)) * 256 + h * 64];
                #pragma unroll
                for (int nt = 0; nt < 4; nt++)
                    dst[nt * 16 + n16] = f2bf(oacc[nt][i] * s);
            }
        }
    }
}

// ---------------------------------------------------------------------------
// Kernel 3: out = LayerNorm(ctx @ fc_w + q), bf16 MFMA + fused LN epilogue.
// grid (500), block 512 = 8 waves in 2x4; block tile 64 rows x 256 cols.
// ---------------------------------------------------------------------------
__global__ __launch_bounds__(512) void final_kernel(
    const u16* __restrict__ ctx, const u16* __restrict__ fcwT,
    const float* __restrict__ qres, const float* __restrict__ g,
    const float* __restrict__ bta, float* __restrict__ out)
{
    __shared__ u16 Xs[64][72];
    __shared__ u16 Ws[256][72];
    __shared__ float red[4][2][64];   // [wc][s1|s2][row]
    __shared__ float murs[2][64];     // [mu|rs][row]

    const int tid  = threadIdx.x;
    const int wvid = tid >> 6, ln = tid & 63;
    const int n16  = ln & 15, quad = ln >> 4;
    const int wr   = wvid >> 2, wc = wvid & 3;   // 2 x 4
    const int row0 = blockIdx.x * 64;

    f32x4 acc[2][4];
    #pragma unroll
    for (int mt = 0; mt < 2; mt++)
        #pragma unroll
        for (int nt = 0; nt < 4; nt++) acc[mt][nt] = (f32x4){0.f, 0.f, 0.f, 0.f};

    for (int kc = 0; kc < 256; kc += 64) {
        // stage X: 64 x 64 bf16
        {
            int idx = tid;
            int m = idx >> 3, k8 = idx & 7;
            *(uint4*)&Xs[m][k8 * 8] =
                *(const uint4*)&ctx[(size_t)(row0 + m) * 256 + kc + k8 * 8];
        }
        // stage W^T: 256 x 64 bf16
        #pragma unroll
        for (int j = 0; j < 4; j++) {
            int idx = tid + 512 * j;
            int n = idx >> 3, k8 = idx & 7;
            *(uint4*)&Ws[n][k8 * 8] = *(const uint4*)&fcwT[n * 256 + kc + k8 * 8];
        }
        __syncthreads();
        #pragma unroll
        for (int ks = 0; ks < 2; ks++) {
            short8 af[2], bfr[4];
            #pragma unroll
            for (int mt = 0; mt < 2; mt++)
                af[mt] = *(const short8*)&Xs[wr * 32 + mt * 16 + n16][ks * 32 + quad * 8];
            #pragma unroll
            for (int nt = 0; nt < 4; nt++)
                bfr[nt] = *(const short8*)&Ws[wc * 64 + nt * 16 + n16][ks * 32 + quad * 8];
            #pragma unroll
            for (int mt = 0; mt < 2; mt++)
                #pragma unroll
                for (int nt = 0; nt < 4; nt++)
                    acc[mt][nt] = __builtin_amdgcn_mfma_f32_16x16x32_bf16(
                        af[mt], bfr[nt], acc[mt][nt], 0, 0, 0);
        }
        __syncthreads();
    }

    // residual add
    #pragma unroll
    for (int mt = 0; mt < 2; mt++) {
        int m0 = row0 + wr * 32 + mt * 16 + quad * 4;
        #pragma unroll
        for (int i = 0; i < 4; i++) {
            const float* rp = &qres[(size_t)(m0 + i) * 256 + wc * 64 + n16];
            #pragma unroll
            for (int nt = 0; nt < 4; nt++)
                acc[mt][nt][i] += rp[nt * 16];
        }
    }
    // per-row partial sums -> LDS
    #pragma unroll
    for (int mt = 0; mt < 2; mt++) {
        #pragma unroll
        for (int i = 0; i < 4; i++) {
            float s1 = 0.f, s2 = 0.f;
            #pragma unroll
            for (int nt = 0; nt < 4; nt++) {
                float vv = acc[mt][nt][i];
                s1 += vv; s2 += vv * vv;
            }
            #pragma unroll
            for (int off = 1; off < 16; off <<= 1) {
                s1 += __shfl_xor(s1, off);
                s2 += __shfl_xor(s2, off);
            }
            if (n16 == 0) {
                int r = wr * 32 + mt * 16 + quad * 4 + i;
                red[wc][0][r] = s1;
                red[wc][1][r] = s2;
            }
        }
    }
    __syncthreads();
    if (tid < 64) {
        float S1 = red[0][0][tid] + red[1][0][tid] + red[2][0][tid] + red[3][0][tid];
        float S2 = red[0][1][tid] + red[1][1][tid] + red[2][1][tid] + red[3][1][tid];
        float mu  = S1 * 0.00390625f;
        float var = S2 * 0.00390625f - mu * mu;
        murs[0][tid] = mu;
        murs[1][tid] = rsqrtf(var + 1e-6f);
    }
    __syncthreads();

    float gv[4], bv[4];
    #pragma unroll
    for (int nt = 0; nt < 4; nt++) {
        int col = wc * 64 + nt * 16 + n16;
        gv[nt] = g[col];
        bv[nt] = bta[col];
    }
    #pragma unroll
    for (int mt = 0; mt < 2; mt++) {
        int rb = wr * 32 + mt * 16 + quad * 4;
        #pragma unroll
        for (int i = 0; i < 4; i++) {
            float mu = murs[0][rb + i];
            float rs = murs[1][rb + i];
            float* op = &out[(size_t)(row0 + rb + i) * 256 + wc * 64 + n16];
            #pragma unroll
            for (int nt = 0; nt < 4; nt++)
                op[nt * 16] = (acc[mt][nt][i] - mu) * rs * gv[nt] + bv[nt];
        }
    }
}

// ---------------------------------------------------------------------------
extern "C" void kernel_launch(void* const* d_in, const int* in_sizes, int n_in,
                              void* d_out, int out_size, void* d_ws, size_t ws_size,
                              hipStream_t stream)
{
    const float* q   = (const float*)d_in[0];
    const float* v   = (const float*)d_in[2];
    const float* wqs = (const float*)d_in[3];
    const float* wvs = (const float*)d_in[4];
    const float* w1  = (const float*)d_in[5];
    const float* b1  = (const float*)d_in[6];
    const float* w2  = (const float*)d_in[7];
    const float* b2  = (const float*)d_in[8];
    const float* fcw = (const float*)d_in[9];
    const float* lng = (const float*)d_in[10];
    const float* lnb = (const float*)d_in[11];
    float* out = (float*)d_out;

    u16* qh_bf = (u16*)d_ws;            // 8,200,192 (padded: attn reads rows <512)
    u16* vhT   = qh_bf + 8200192;       // 8,388,608  [bh][64][512]
    u16* w1T   = vhT + 8388608;         // 4,096
    u16* w2T   = w1T + 4096;            // 32,768     [512][64]
    u16* wqT   = w2T + 32768;           // 65,536
    u16* wvT   = wqT + 65536;           // 65,536
    u16* fcwT  = wvT + 65536;           // 65,536
    u16* ctx   = fcwT + 65536;          // 8,192,000

    prep_kernel <<<dim3(256),    256, 0, stream>>>(wqs, wvs, fcw, w1, w2,
                                                   wqT, wvT, fcwT, w1T, w2T, vhT);
    proj_kernel <<<dim3(500, 2), 512, 0, stream>>>(q, v, wqT, wvT, qh_bf, vhT);
    attn_kernel <<<dim3(256, 8), 256, 0, stream>>>(qh_bf, vhT, w1T, b1, w2T, b2, ctx);
    final_kernel<<<dim3(500),    512, 0, stream>>>(ctx, fcwT, q, lng, lnb, out);
}

// Round 6
// 236.732 us; speedup vs baseline: 1.3052x; 1.0089x over previous
//
#include <hip/hip_runtime.h>
#include <hip/hip_bf16.h>
#include <math.h>

#define B_   64
#define L_   500
#define F_   256
#define H_   4
#define DK   64

typedef unsigned short u16;
typedef unsigned int   u32;
typedef __attribute__((ext_vector_type(8))) short short8;
typedef __attribute__((ext_vector_type(4))) float f32x4;

static __device__ __forceinline__ u16 f2bf(float f) {
    u32 u = __float_as_uint(f);
    u32 r = (u + 0x7FFFu + ((u >> 16) & 1u)) >> 16;
    return (u16)r;
}
// packed bf16 pair via HW v_cvt_pk_bf16_f32 (HIP intrinsic, RNE).
// low u16 = bf16(a), high u16 = bf16(b).
static __device__ __forceinline__ u32 pk2(float a, float b) {
    __hip_bfloat162 h = __float22bfloat162_rn(make_float2(a, b));
    u32 r; __builtin_memcpy(&r, &h, sizeof(r));
    return r;
}

// ---------------------------------------------------------------------------
// Prep: bf16 transposed weights.
//  wqT/wvT/fcwT [256][256] ([n][k]); w1T[64][64]; w2T[512][64] (n>=500 -> 0)
//  Also zero-fills vhT cols 500..511 (attn chunk-3 staging reads them).
// ---------------------------------------------------------------------------
__global__ __launch_bounds__(256) void prep_kernel(
    const float* __restrict__ wq, const float* __restrict__ wv,
    const float* __restrict__ fcw, const float* __restrict__ w1,
    const float* __restrict__ w2,
    u16* __restrict__ wqT, u16* __restrict__ wvT, u16* __restrict__ fcwT,
    u16* __restrict__ w1T, u16* __restrict__ w2T, u16* __restrict__ vhT)
{
    int t = blockIdx.x * 256 + threadIdx.x;
    int stride = gridDim.x * 256;
    for (int i = t; i < 256 * 256; i += stride) {
        int n = i >> 8, k = i & 255;
        wqT[i]  = f2bf(wq[k * 256 + n]);
        wvT[i]  = f2bf(wv[k * 256 + n]);
        fcwT[i] = f2bf(fcw[k * 256 + n]);
    }
    for (int i = t; i < 64 * 64; i += stride) {
        int n = i >> 6, k = i & 63;
        w1T[i] = f2bf(w1[k * 64 + n]);
    }
    for (int i = t; i < 512 * 64; i += stride) {
        int n = i >> 6, k = i & 63;
        w2T[i] = f2bf(n < 500 ? w2[k * 500 + n] : 0.f);
    }
    // zero vhT padding cols l in [500,512) for every (bh, d)
    for (int i = t; i < 256 * 64 * 12; i += stride) {
        int l  = 500 + (i % 12);
        int d  = (i / 12) & 63;
        int bh = i / (12 * 64);
        vhT[(size_t)(bh * 64 + d) * 512 + l] = 0;
    }
}

// ---------------------------------------------------------------------------
// Kernel 1: head projections, bf16 MFMA.
// grid (500, 2), block 512 = 8 waves in 2x4; block tile 64 rows x 256 cols.
// wave tile 32 x 64.  which=0: qh_bf [bh][500][64]; which=1: vhT [bh][64][512]
// ---------------------------------------------------------------------------
__global__ __launch_bounds__(512) void proj_kernel(
    const float* __restrict__ q, const float* __restrict__ v,
    const u16* __restrict__ wqT, const u16* __restrict__ wvT,
    u16* __restrict__ qh_bf, u16* __restrict__ vhT)
{
    const int which = blockIdx.y;
    const float* __restrict__ x = which ? v : q;
    const u16*   __restrict__ wT = which ? wvT : wqT;

    __shared__ u16 Xs[64][72];    // [m][k], pad 144 B
    __shared__ u16 Ws[256][72];   // [n][k], pad 144 B

    const int tid  = threadIdx.x;
    const int wvid = tid >> 6, ln = tid & 63;
    const int n16  = ln & 15, quad = ln >> 4;
    const int wr   = wvid >> 2, wc = wvid & 3;   // 2 x 4
    const int row0 = blockIdx.x * 64;

    f32x4 acc[2][4];
    #pragma unroll
    for (int mt = 0; mt < 2; mt++)
        #pragma unroll
        for (int nt = 0; nt < 4; nt++) acc[mt][nt] = (f32x4){0.f, 0.f, 0.f, 0.f};

    for (int kc = 0; kc < 256; kc += 64) {
        // stage X (fp32 -> bf16 via packed cvt): 64 x 64
        #pragma unroll
        for (int j = 0; j < 2; j++) {
            int idx = tid + 512 * j;
            int m = idx >> 4, k4 = idx & 15;
            float4 a = *(const float4*)&x[(size_t)(row0 + m) * 256 + kc + k4 * 4];
            uint2 uu = { pk2(a.x, a.y), pk2(a.z, a.w) };
            *(uint2*)&Xs[m][k4 * 4] = uu;
        }
        // stage W^T: 256 x 64 bf16
        #pragma unroll
        for (int j = 0; j < 4; j++) {
            int idx = tid + 512 * j;
            int n = idx >> 3, k8 = idx & 7;
            *(uint4*)&Ws[n][k8 * 8] = *(const uint4*)&wT[n * 256 + kc + k8 * 8];
        }
        __syncthreads();
        #pragma unroll
        for (int ks = 0; ks < 2; ks++) {
            short8 af[2], bfr[4];
            #pragma unroll
            for (int mt = 0; mt < 2; mt++)
                af[mt] = *(const short8*)&Xs[wr * 32 + mt * 16 + n16][ks * 32 + quad * 8];
            #pragma unroll
            for (int nt = 0; nt < 4; nt++)
                bfr[nt] = *(const short8*)&Ws[wc * 64 + nt * 16 + n16][ks * 32 + quad * 8];
            #pragma unroll
            for (int mt = 0; mt < 2; mt++)
                #pragma unroll
                for (int nt = 0; nt < 4; nt++)
                    acc[mt][nt] = __builtin_amdgcn_mfma_f32_16x16x32_bf16(
                        af[mt], bfr[nt], acc[mt][nt], 0, 0, 0);
        }
        __syncthreads();
    }

    // h = wc (64-col groups), d = nt*16 + n16
    if (which == 0) {
        #pragma unroll
        for (int mt = 0; mt < 2; mt++) {
            int m0 = row0 + wr * 32 + mt * 16 + quad * 4;   // mult of 4
            int b  = m0 / 500;
            int l0 = m0 - 500 * b;                           // group never straddles b
            #pragma unroll
            for (int nt = 0; nt < 4; nt++) {
                int d = nt * 16 + n16;
                u16* dst = qh_bf + ((size_t)((b * 4 + wc) * 500 + l0)) * 64 + d;
                u32 p01 = pk2(acc[mt][nt][0], acc[mt][nt][1]);
                u32 p23 = pk2(acc[mt][nt][2], acc[mt][nt][3]);
                dst[0]   = (u16)p01;
                dst[64]  = (u16)(p01 >> 16);
                dst[128] = (u16)p23;
                dst[192] = (u16)(p23 >> 16);
            }
        }
    } else {
        #pragma unroll
        for (int mt = 0; mt < 2; mt++) {
            int m0 = row0 + wr * 32 + mt * 16 + quad * 4;
            int b  = m0 / 500;
            int l0 = m0 - 500 * b;
            #pragma unroll
            for (int nt = 0; nt < 4; nt++) {
                int d = nt * 16 + n16;
                uint2 uu = { pk2(acc[mt][nt][0], acc[mt][nt][1]),
                             pk2(acc[mt][nt][2], acc[mt][nt][3]) };
                *(uint2*)&vhT[((size_t)((b * 4 + wc) * 64 + d)) * 512 + l0] = uu;
            }
        }
    }
}

// ---------------------------------------------------------------------------
// Kernel 2: dense-synthesizer attention (r5 structure, cvt_pk converts).
// grid (256 bh, 8 row-chunks), block 256 (4 waves x 16 rows).
// - Phase A barrier-free in per-wave-private P region.
// - Phase B: w2 LDS double-buffer, issue-early / write-late.
// - Full softmax over acc[32]; V0 loads issued just before it.
// - Phase C: V double-buffered; V(cc+1) loads issued between P-write and
//   PV, ds_write after PV, one sync per chunk.
// - V buffers alias the dead w2 LDS region. LDS = 54,272 B.
// Occupancy note: 128 VGPR + 128 AGPR (acc[32]) = 256 -> 2 waves/SIMD;
// register-bound, not LDS-bound.
// ---------------------------------------------------------------------------
__global__ __launch_bounds__(256) void attn_kernel(
    const u16* __restrict__ qh, const u16* __restrict__ vhT,
    const u16* __restrict__ w1T, const float* __restrict__ b1,
    const u16* __restrict__ w2T, const float* __restrict__ b2,
    u16* __restrict__ ctx)
{
    __shared__ __align__(16) char lds_raw[36864];   // w2 dbuf | V dbuf (union)
    __shared__ __align__(16) u16 pls[4][16][136];   // per-wave s/P tile
    u16 (*w2s)[128][72] = (u16 (*)[128][72]) lds_raw;           // [2][128][72]
    u16 (*vbufA)[136]   = (u16 (*)[136]) lds_raw;               // [64][136]
    u16 (*vbufB)[136]   = (u16 (*)[136]) (lds_raw + 17408);     // [64][136]

    const int tid  = threadIdx.x;
    const int wv   = tid >> 6;
    const int ln   = tid & 63;
    const int n16  = ln & 15;
    const int quad = ln >> 4;
    const int bh   = blockIdx.x;
    const int r0   = blockIdx.y * 64 + wv * 16;

    const u16* __restrict__ vgbase = vhT + (size_t)bh * 64 * 512;
    u16 (*pw)[136] = pls[wv];

    // ---- issue w2 chunk-0 staging loads (land during Phase A) ----
    uint4 rw[4];
    #pragma unroll
    for (int j = 0; j < 4; j++) {
        int idx = tid + 256 * j;
        rw[j] = *(const uint4*)&w2T[idx * 8];
    }

    // ---- Phase A: s = relu(qh @ w1 + b1) -> private LDS -> A-frags ----
    short8 sa0, sa1;
    {
        const u16* qbase = qh + ((size_t)(bh * 500 + r0 + n16)) * 64;
        short8 a0 = *(const short8*)(qbase + quad * 8);
        short8 a1 = *(const short8*)(qbase + 32 + quad * 8);
        #pragma unroll
        for (int nt = 0; nt < 4; nt++) {
            const u16* wb = w1T + (nt * 16 + n16) * 64;
            short8 bb0 = *(const short8*)(wb + quad * 8);
            short8 bb1 = *(const short8*)(wb + 32 + quad * 8);
            f32x4 c4 = {0.f, 0.f, 0.f, 0.f};
            c4 = __builtin_amdgcn_mfma_f32_16x16x32_bf16(a0, bb0, c4, 0, 0, 0);
            c4 = __builtin_amdgcn_mfma_f32_16x16x32_bf16(a1, bb1, c4, 0, 0, 0);
            float bias = b1[nt * 16 + n16];
            int col = nt * 16 + n16;
            u32 p01 = pk2(fmaxf(c4[0] + bias, 0.f), fmaxf(c4[1] + bias, 0.f));
            u32 p23 = pk2(fmaxf(c4[2] + bias, 0.f), fmaxf(c4[3] + bias, 0.f));
            pw[quad * 4 + 0][col] = (u16)p01;
            pw[quad * 4 + 1][col] = (u16)(p01 >> 16);
            pw[quad * 4 + 2][col] = (u16)p23;
            pw[quad * 4 + 3][col] = (u16)(p23 >> 16);
        }
        sa0 = *(const short8*)&pw[n16][quad * 8];
        sa1 = *(const short8*)&pw[n16][32 + quad * 8];
    }

    // ---- write w2 chunk 0, publish ----
    #pragma unroll
    for (int j = 0; j < 4; j++) {
        int idx = tid + 256 * j;
        *(uint4*)&w2s[0][idx >> 3][(idx & 7) * 8] = rw[j];
    }
    __syncthreads();                                     // sync 1

    // ---- Phase B: logits = s @ w2 + b2, w2 double-buffered, write-late ----
    f32x4 acc[32];
    for (int cc = 0; cc < 4; cc++) {
        if (cc < 3) {
            const u16* src = w2T + (cc + 1) * 8192;
            #pragma unroll
            for (int j = 0; j < 4; j++) {
                int idx = tid + 256 * j;
                rw[j] = *(const uint4*)&src[idx * 8];
            }
        }
        u16 (*buf)[72] = w2s[cc & 1];
        #pragma unroll
        for (int t = 0; t < 8; t++) {
            int nt = cc * 8 + t;
            short8 bb0 = *(const short8*)&buf[t * 16 + n16][quad * 8];
            short8 bb1 = *(const short8*)&buf[t * 16 + n16][32 + quad * 8];
            f32x4 c = {0.f, 0.f, 0.f, 0.f};
            c = __builtin_amdgcn_mfma_f32_16x16x32_bf16(sa0, bb0, c, 0, 0, 0);
            c = __builtin_amdgcn_mfma_f32_16x16x32_bf16(sa1, bb1, c, 0, 0, 0);
            int col = cc * 128 + t * 16 + n16;
            float bias = (col < 500) ? b2[col] : -INFINITY;
            #pragma unroll
            for (int i = 0; i < 4; i++) c[i] += bias;
            acc[nt] = c;
        }
        if (cc < 3) {
            #pragma unroll
            for (int j = 0; j < 4; j++) {
                int idx = tid + 256 * j;
                *(uint4*)&w2s[(cc + 1) & 1][idx >> 3][(idx & 7) * 8] = rw[j];
            }
        }
        __syncthreads();                                 // sync 2-5
    }

    // ---- issue V chunk-0 loads (softmax covers their latency) ----
    short8 rV[4];
    #pragma unroll
    for (int jj = 0; jj < 4; jj++) {
        int u = tid + 256 * jj, d = u >> 4, kk = (u & 15) * 8;
        rV[jj] = *(const short8*)&vgbase[(size_t)d * 512 + kk];
    }

    // ---- softmax stats (P unnormalized; fold 1/sum into epilogue) ----
    float inv[4];
    {
        float mx[4], sm[4];
        #pragma unroll
        for (int i = 0; i < 4; i++) mx[i] = acc[0][i];
        #pragma unroll
        for (int nt = 1; nt < 32; nt++)
            #pragma unroll
            for (int i = 0; i < 4; i++) mx[i] = fmaxf(mx[i], acc[nt][i]);
        #pragma unroll
        for (int off = 1; off < 16; off <<= 1)
            #pragma unroll
            for (int i = 0; i < 4; i++) mx[i] = fmaxf(mx[i], __shfl_xor(mx[i], off));
        #pragma unroll
        for (int i = 0; i < 4; i++) sm[i] = 0.f;
        #pragma unroll
        for (int nt = 0; nt < 32; nt++)
            #pragma unroll
            for (int i = 0; i < 4; i++) {
                float e = __expf(acc[nt][i] - mx[i]);
                acc[nt][i] = e;
                sm[i] += e;
            }
        #pragma unroll
        for (int off = 1; off < 16; off <<= 1)
            #pragma unroll
            for (int i = 0; i < 4; i++) sm[i] += __shfl_xor(sm[i], off);
        #pragma unroll
        for (int i = 0; i < 4; i++) inv[i] = 1.f / sm[i];
    }

    // ---- write V0 -> bufA, publish ----
    #pragma unroll
    for (int jj = 0; jj < 4; jj++) {
        int u = tid + 256 * jj, d = u >> 4, kk = (u & 15) * 8;
        *(short8*)&vbufA[d][kk] = rV[jj];
    }
    __syncthreads();                                     // sync 6

    // ---- Phase C: out = P @ vh, V double-buffered ----
    f32x4 oacc[4];
    #pragma unroll
    for (int nt = 0; nt < 4; nt++) oacc[nt] = (f32x4){0.f, 0.f, 0.f, 0.f};

    for (int cc = 0; cc < 4; cc++) {
        u16 (*vb)[136] = (cc & 1) ? vbufB : vbufA;
        u16 (*vn)[136] = (cc & 1) ? vbufA : vbufB;

        // P for this chunk (per-wave private, no barrier), packed converts
        #pragma unroll
        for (int t = 0; t < 8; t++) {
            int nt = cc * 8 + t;
            int c  = t * 16 + n16;
            u32 p01 = pk2(acc[nt][0], acc[nt][1]);
            u32 p23 = pk2(acc[nt][2], acc[nt][3]);
            pw[quad * 4 + 0][c] = (u16)p01;
            pw[quad * 4 + 1][c] = (u16)(p01 >> 16);
            pw[quad * 4 + 2][c] = (u16)p23;
            pw[quad * 4 + 3][c] = (u16)(p23 >> 16);
        }
        // issue V(cc+1) loads; PV below covers their latency
        if (cc < 3) {
            #pragma unroll
            for (int jj = 0; jj < 4; jj++) {
                int u = tid + 256 * jj, d = u >> 4, kk = (u & 15) * 8;
                rV[jj] = *(const short8*)&vgbase[(size_t)d * 512 + (cc + 1) * 128 + kk];
            }
        }
        // PV MFMAs
        #pragma unroll
        for (int ks = 0; ks < 4; ks++) {
            short8 pa = *(const short8*)&pw[n16][ks * 32 + quad * 8];
            #pragma unroll
            for (int nt = 0; nt < 4; nt++) {
                short8 vvf = *(const short8*)&vb[nt * 16 + n16][ks * 32 + quad * 8];
                oacc[nt] = __builtin_amdgcn_mfma_f32_16x16x32_bf16(pa, vvf, oacc[nt], 0, 0, 0);
            }
        }
        // write-late V(cc+1) into the other buffer (WAR drained by prev sync)
        if (cc < 3) {
            #pragma unroll
            for (int jj = 0; jj < 4; jj++) {
                int u = tid + 256 * jj, d = u >> 4, kk = (u & 15) * 8;
                *(short8*)&vn[d][kk] = rV[jj];
            }
            __syncthreads();                             // sync 7-9
        }
    }

    // ---- epilogue: scale, write ctx bf16 (packed converts) ----
    {
        const int b = bh >> 2, h = bh & 3;
        #pragma unroll
        for (int i = 0; i < 4; i++) {
            int lrow = r0 + quad * 4 + i;
            if (lrow < 500) {
                float s = inv[i];
                u16* dst = &ctx[((size_t)(b * 500 + lrow)) * 256 + h * 64];
                u32 a01 = pk2(oacc[0][i] * s, oacc[1][i] * s);
                u32 a23 = pk2(oacc[2][i] * s, oacc[3][i] * s);
                dst[0 * 16 + n16] = (u16)a01;
                dst[1 * 16 + n16] = (u16)(a01 >> 16);
                dst[2 * 16 + n16] = (u16)a23;
                dst[3 * 16 + n16] = (u16)(a23 >> 16);
            }
        }
    }
}

// ---------------------------------------------------------------------------
// Kernel 3: out = LayerNorm(ctx @ fc_w + q), bf16 MFMA + fused LN epilogue.
// grid (500), block 512 = 8 waves in 2x4; block tile 64 rows x 256 cols.
// ---------------------------------------------------------------------------
__global__ __launch_bounds__(512) void final_kernel(
    const u16* __restrict__ ctx, const u16* __restrict__ fcwT,
    const float* __restrict__ qres, const float* __restrict__ g,
    const float* __restrict__ bta, float* __restrict__ out)
{
    __shared__ u16 Xs[64][72];
    __shared__ u16 Ws[256][72];
    __shared__ float red[4][2][64];   // [wc][s1|s2][row]
    __shared__ float murs[2][64];     // [mu|rs][row]

    const int tid  = threadIdx.x;
    const int wvid = tid >> 6, ln = tid & 63;
    const int n16  = ln & 15, quad = ln >> 4;
    const int wr   = wvid >> 2, wc = wvid & 3;   // 2 x 4
    const int row0 = blockIdx.x * 64;

    f32x4 acc[2][4];
    #pragma unroll
    for (int mt = 0; mt < 2; mt++)
        #pragma unroll
        for (int nt = 0; nt < 4; nt++) acc[mt][nt] = (f32x4){0.f, 0.f, 0.f, 0.f};

    for (int kc = 0; kc < 256; kc += 64) {
        // stage X: 64 x 64 bf16
        {
            int idx = tid;
            int m = idx >> 3, k8 = idx & 7;
            *(uint4*)&Xs[m][k8 * 8] =
                *(const uint4*)&ctx[(size_t)(row0 + m) * 256 + kc + k8 * 8];
        }
        // stage W^T: 256 x 64 bf16
        #pragma unroll
        for (int j = 0; j < 4; j++) {
            int idx = tid + 512 * j;
            int n = idx >> 3, k8 = idx & 7;
            *(uint4*)&Ws[n][k8 * 8] = *(const uint4*)&fcwT[n * 256 + kc + k8 * 8];
        }
        __syncthreads();
        #pragma unroll
        for (int ks = 0; ks < 2; ks++) {
            short8 af[2], bfr[4];
            #pragma unroll
            for (int mt = 0; mt < 2; mt++)
                af[mt] = *(const short8*)&Xs[wr * 32 + mt * 16 + n16][ks * 32 + quad * 8];
            #pragma unroll
            for (int nt = 0; nt < 4; nt++)
                bfr[nt] = *(const short8*)&Ws[wc * 64 + nt * 16 + n16][ks * 32 + quad * 8];
            #pragma unroll
            for (int mt = 0; mt < 2; mt++)
                #pragma unroll
                for (int nt = 0; nt < 4; nt++)
                    acc[mt][nt] = __builtin_amdgcn_mfma_f32_16x16x32_bf16(
                        af[mt], bfr[nt], acc[mt][nt], 0, 0, 0);
        }
        __syncthreads();
    }

    // residual add
    #pragma unroll
    for (int mt = 0; mt < 2; mt++) {
        int m0 = row0 + wr * 32 + mt * 16 + quad * 4;
        #pragma unroll
        for (int i = 0; i < 4; i++) {
            const float* rp = &qres[(size_t)(m0 + i) * 256 + wc * 64 + n16];
            #pragma unroll
            for (int nt = 0; nt < 4; nt++)
                acc[mt][nt][i] += rp[nt * 16];
        }
    }
    // per-row partial sums -> LDS
    #pragma unroll
    for (int mt = 0; mt < 2; mt++) {
        #pragma unroll
        for (int i = 0; i < 4; i++) {
            float s1 = 0.f, s2 = 0.f;
            #pragma unroll
            for (int nt = 0; nt < 4; nt++) {
                float vv = acc[mt][nt][i];
                s1 += vv; s2 += vv * vv;
            }
            #pragma unroll
            for (int off = 1; off < 16; off <<= 1) {
                s1 += __shfl_xor(s1, off);
                s2 += __shfl_xor(s2, off);
            }
            if (n16 == 0) {
                int r = wr * 32 + mt * 16 + quad * 4 + i;
                red[wc][0][r] = s1;
                red[wc][1][r] = s2;
            }
        }
    }
    __syncthreads();
    if (tid < 64) {
        float S1 = red[0][0][tid] + red[1][0][tid] + red[2][0][tid] + red[3][0][tid];
        float S2 = red[0][1][tid] + red[1][1][tid] + red[2][1][tid] + red[3][1][tid];
        float mu  = S1 * 0.00390625f;
        float var = S2 * 0.00390625f - mu * mu;
        murs[0][tid] = mu;
        murs[1][tid] = rsqrtf(var + 1e-6f);
    }
    __syncthreads();

    float gv[4], bv[4];
    #pragma unroll
    for (int nt = 0; nt < 4; nt++) {
        int col = wc * 64 + nt * 16 + n16;
        gv[nt] = g[col];
        bv[nt] = bta[col];
    }
    #pragma unroll
    for (int mt = 0; mt < 2; mt++) {
        int rb = wr * 32 + mt * 16 + quad * 4;
        #pragma unroll
        for (int i = 0; i < 4; i++) {
            float mu = murs[0][rb + i];
            float rs = murs[1][rb + i];
            float* op = &out[(size_t)(row0 + rb + i) * 256 + wc * 64 + n16];
            #pragma unroll
            for (int nt = 0; nt < 4; nt++)
                op[nt * 16] = (acc[mt][nt][i] - mu) * rs * gv[nt] + bv[nt];
        }
    }
}

// ---------------------------------------------------------------------------
extern "C" void kernel_launch(void* const* d_in, const int* in_sizes, int n_in,
                              void* d_out, int out_size, void* d_ws, size_t ws_size,
                              hipStream_t stream)
{
    const float* q   = (const float*)d_in[0];
    const float* v   = (const float*)d_in[2];
    const float* wqs = (const float*)d_in[3];
    const float* wvs = (const float*)d_in[4];
    const float* w1  = (const float*)d_in[5];
    const float* b1  = (const float*)d_in[6];
    const float* w2  = (const float*)d_in[7];
    const float* b2  = (const float*)d_in[8];
    const float* fcw = (const float*)d_in[9];
    const float* lng = (const float*)d_in[10];
    const float* lnb = (const float*)d_in[11];
    float* out = (float*)d_out;

    u16* qh_bf = (u16*)d_ws;            // 8,200,192 (padded: attn reads rows <512)
    u16* vhT   = qh_bf + 8200192;       // 8,388,608  [bh][64][512]
    u16* w1T   = vhT + 8388608;         // 4,096
    u16* w2T   = w1T + 4096;            // 32,768     [512][64]
    u16* wqT   = w2T + 32768;           // 65,536
    u16* wvT   = wqT + 65536;           // 65,536
    u16* fcwT  = wvT + 65536;           // 65,536
    u16* ctx   = fcwT + 65536;          // 8,192,000

    prep_kernel <<<dim3(256),    256, 0, stream>>>(wqs, wvs, fcw, w1, w2,
                                                   wqT, wvT, fcwT, w1T, w2T, vhT);
    proj_kernel <<<dim3(500, 2), 512, 0, stream>>>(q, v, wqT, wvT, qh_bf, vhT);
    attn_kernel <<<dim3(256, 8), 256, 0, stream>>>(qh_bf, vhT, w1T, b1, w2T, b2, ctx);
    final_kernel<<<dim3(500),    512, 0, stream>>>(ctx, fcwT, q, lng, lnb, out);
}